// Round 11
// baseline (663.791 us; speedup 1.0000x reference)
//
#include <hip/hip_runtime.h>
#include <hip/hip_bf16.h>

#define CH    192
#define NB    4
#define NHH   256
#define NWW   256
#define NPOS  (NB*NHH*NWW)   // 262144
#define HEADS 8
#define DH    24
#define WIN   16
#define PS    ((size_t)NPOS*DH)   // head-plane stride (elems)

typedef unsigned short u16;
typedef __bf16 bf16x8 __attribute__((ext_vector_type(8)));
typedef float  f32x4  __attribute__((ext_vector_type(4)));
typedef u16    u16x8  __attribute__((ext_vector_type(8)));
typedef u16    u16x4  __attribute__((ext_vector_type(4)));

__device__ __forceinline__ float b2f(u16 h) {
    union { unsigned int u; float f; } x; x.u = ((unsigned int)h) << 16; return x.f;
}
__device__ __forceinline__ u16 f2b(float f) {   // RNE
    union { float f; unsigned int u; } x; x.f = f;
    return (u16)((x.u + 0x7fffu + ((x.u >> 16) & 1u)) >> 16);
}

// ---------------------------------------------------------------------------
// P0: pack 4 weight matrices (fp32 [o][i]) into MFMA fragment order, bf16.
// ---------------------------------------------------------------------------
__global__ __launch_bounds__(256) void prep_weights(
    const float* __restrict__ w0, const float* __restrict__ w1,
    const float* __restrict__ w2, const float* __restrict__ w3,
    u16* __restrict__ pack)
{
    const int t = blockIdx.x * 256 + threadIdx.x;   // 18432 total
    const int lane = t & 63, g = t >> 6;            // g: 0..287
    const int mat = g / 72;
    const float* w = (mat == 0) ? w0 : (mat == 1) ? w1 : (mat == 2) ? w2 : w3;
    const int nt = (g / 6) % 12, ks = g % 6;
    const float* src = w + (nt*16 + (lane & 15)) * CH + ks*32 + (lane >> 4) * 8;
    const float4 a = *(const float4*)(src);
    const float4 b = *(const float4*)(src + 4);
    u16x8 o;
    o[0]=f2b(a.x); o[1]=f2b(a.y); o[2]=f2b(a.z); o[3]=f2b(a.w);
    o[4]=f2b(b.x); o[5]=f2b(b.y); o[6]=f2b(b.z); o[7]=f2b(b.w);
    *(u16x8*)(pack + (size_t)g*512 + lane*8) = o;
}

// ---------------------------------------------------------------------------
// K1: fused LayerNorm + QKV MFMA GEMM (operand-swapped: D = W * X^T).
// M=32 tile, At swizzled, 25.1 KB LDS, 6 blk/CU. (unchanged)
// ---------------------------------------------------------------------------
__global__ __launch_bounds__(256, 6) void ln_qkv_gemm(
    const float* __restrict__ x, const float* __restrict__ lng, const float* __restrict__ lnb,
    const u16* __restrict__ bpack,
    u16* __restrict__ y0, u16* __restrict__ y1, u16* __restrict__ y2)
{
    __shared__ __align__(16) u16 At[32*192];    // 12,288 B (swizzled)
    __shared__ __align__(16) u16 St32[32*200];  // 12,800 B
    const int t = threadIdx.x, l = t & 63, w = t >> 6;
    const int lr = l & 15, lg = l >> 4;
    const size_t p0 = (size_t)blockIdx.x * 32;

    // ---- LN phase: 8 lanes per row (24 ch each), shfl-reduce, bf16 -> At ----
    {
        const int row = t >> 3, part = t & 7;
        const float* xp = x + (p0 + row) * CH + part * 24;
        float vals[24];
#pragma unroll
        for (int j = 0; j < 6; ++j) {
            float4 v4 = *(const float4*)(xp + j * 4);
            vals[j*4+0]=v4.x; vals[j*4+1]=v4.y; vals[j*4+2]=v4.z; vals[j*4+3]=v4.w;
        }
        float s = 0.f, s2 = 0.f;
#pragma unroll
        for (int j = 0; j < 24; ++j) { s += vals[j]; s2 += vals[j]*vals[j]; }
        s += __shfl_xor(s, 1);  s2 += __shfl_xor(s2, 1);
        s += __shfl_xor(s, 2);  s2 += __shfl_xor(s2, 2);
        s += __shfl_xor(s, 4);  s2 += __shfl_xor(s2, 4);
        const float mu = s * (1.f/192.f);
        const float rs = rsqrtf(s2 * (1.f/192.f) - mu*mu + 1e-5f);
#pragma unroll
        for (int jb = 0; jb < 3; ++jb) {
            u16x8 o;
#pragma unroll
            for (int j = 0; j < 8; ++j) {
                const int c = part*24 + jb*8 + j;
                o[j] = f2b((vals[jb*8+j] - mu) * rs * lng[c] + lnb[c]);
            }
            const int cb = part*3 + jb;               // 0..23
            *(u16x8*)&At[row*192 + (cb ^ (row & 7))*8] = o;
        }
    }
    __syncthreads();

    // ---- GEMM over 3 weight matrices (operand-swapped) ----
    for (int mat = 0; mat < 3; ++mat) {
        u16* yb = (mat == 0) ? y0 : (mat == 1) ? y1 : y2;
        f32x4 acc[2][3];
#pragma unroll
        for (int mt = 0; mt < 2; ++mt)
#pragma unroll
            for (int nt = 0; nt < 3; ++nt) acc[mt][nt] = (f32x4){0.f,0.f,0.f,0.f};
        const u16* bp = bpack + (size_t)mat*36864 + (size_t)w*3*3072 + l*8;
#pragma unroll
        for (int ks = 0; ks < 6; ++ks) {
            bf16x8 wf[3], xf[2];
#pragma unroll
            for (int nt = 0; nt < 3; ++nt)
                wf[nt] = *(const bf16x8*)(bp + (size_t)nt*3072 + ks*512);
#pragma unroll
            for (int mt = 0; mt < 2; ++mt)
                xf[mt] = *(const bf16x8*)&At[(mt*16 + lr)*192 + ((ks*4 + lg) ^ (lr & 7))*8];
#pragma unroll
            for (int mt = 0; mt < 2; ++mt)
#pragma unroll
                for (int nt = 0; nt < 3; ++nt)   // D = W-frag * X-frag
                    acc[mt][nt] = __builtin_amdgcn_mfma_f32_16x16x32_bf16(
                        wf[nt], xf[mt], acc[mt][nt], 0, 0, 0);
        }
        // D layout: position = mt*16 + lr, channel = (w*3+nt)*16 + lg*4 + reg
        __syncthreads();                 // St32 free (prev mat's drain done)
#pragma unroll
        for (int mt = 0; mt < 2; ++mt)
#pragma unroll
            for (int nt = 0; nt < 3; ++nt) {
                u16x4 pk;
                pk[0] = f2b(acc[mt][nt][0]); pk[1] = f2b(acc[mt][nt][1]);
                pk[2] = f2b(acc[mt][nt][2]); pk[3] = f2b(acc[mt][nt][3]);
                *(u16x4*)&St32[(mt*16 + lr)*200 + (w*3 + nt)*16 + lg*4] = pk;
            }
        __syncthreads();
        // drain: 256 threads = 8 heads x 32 rows, 48B contiguous each
        {
            const int hh = t >> 5, r = t & 31;
            u16* dst = yb + (size_t)hh*PS + (p0 + r)*DH;
#pragma unroll
            for (int j8 = 0; j8 < 3; ++j8)
                *(u16x8*)(dst + j8*8) = *(const u16x8*)&St32[r*200 + hh*24 + j8*8];
        }
    }
}

// ---------------------------------------------------------------------------
// K2: 3x3 depthwise conv, bf16, fp32 accum. Block-uniform (tensor,c8):
// grid.x = 1024 px-blocks x 9 subs; swizzle wid=(bx&7)*1152+(bx>>3) keeps
// each XCD on a contiguous pixel band with all 9 subs temporally adjacent
// (input lines fetched once per XCD, partial-line writes merge in L2).
// Weights: 72 contiguous block-uniform floats -> s_load into SGPRs; FMA
// uses scalar operand. No LDS, no barrier. iv[9] loads batched (R10 win).
// ---------------------------------------------------------------------------
__global__ __launch_bounds__(256) void dwconv_all(
    const u16* __restrict__ in0, const u16* __restrict__ in1, const u16* __restrict__ in2,
    const float* __restrict__ w0, const float* __restrict__ w1, const float* __restrict__ w2,
    u16* __restrict__ out0, u16* __restrict__ out1, u16* __restrict__ out2,
    const u16* __restrict__ zpage)
{
    const int bx = blockIdx.x;               // 9216 = 8 XCD * 1152
    const int wid = (bx & 7)*1152 + (bx >> 3);
    const int pxb = wid / 9, sub = wid - pxb*9;
    const int tensor = sub / 3, c8 = sub - tensor*3;
    const int h = blockIdx.y;
    const u16* in  = (tensor == 0) ? in0  : (tensor == 1) ? in1  : in2;
    const float* wdw = (tensor == 0) ? w0 : (tensor == 1) ? w1 : w2;
    u16* out       = (tensor == 0) ? out0 : (tensor == 1) ? out1 : out2;

    // block-uniform weights -> scalar regs (72 contiguous floats [c][tap])
    const float* wb = wdw + h*216 + c8*72;
    float wsc[72];
#pragma unroll
    for (int i = 0; i < 72; ++i) wsc[i] = wb[i];

    const int t = threadIdx.x;
    const int p = pxb*256 + t;               // pixel id
    const int x = p & 255, y = (p >> 8) & 255, b = p >> 16;
    const size_t plane = (size_t)h * PS;

    // issue all 9 tap loads (borders -> zero page), then one wait
    u16x8 iv[9];
#pragma unroll
    for (int ky = 0; ky < 3; ++ky) {
        const int yy = y + ky - 1;
        const bool oky = (yy >= 0) && (yy < NHH);
        const u16* rowp = in + plane + (size_t)((b*NHH + yy)*NWW + x)*DH + c8*8;
#pragma unroll
        for (int kx = 0; kx < 3; ++kx) {
            const int xx = x + kx - 1;
            const bool ok = oky && (xx >= 0) && (xx < NWW);
            const u16* src = ok ? (rowp + (kx - 1)*DH) : zpage;
            iv[ky*3 + kx] = *(const u16x8*)src;
        }
    }
    float acc[8] = {0,0,0,0,0,0,0,0};
#pragma unroll
    for (int tap = 0; tap < 9; ++tap)
#pragma unroll
        for (int j = 0; j < 8; ++j)
            acc[j] += b2f(iv[tap][j]) * wsc[j*9 + tap];
    u16x8 ov;
#pragma unroll
    for (int j = 0; j < 8; ++j) ov[j] = f2b(acc[j]);
    *(u16x8*)(out + plane + (size_t)p*DH + c8*8) = ov;
}

// ---------------------------------------------------------------------------
// K3: per-(window, head) channel attention; head-separated I/O.
// ---------------------------------------------------------------------------
__global__ __launch_bounds__(256) void attn_kernel(
    const u16* __restrict__ q, const u16* __restrict__ k, const u16* __restrict__ v,
    const float* __restrict__ rescale, u16* __restrict__ out)
{
    __shared__ float qt[DH][260];
    __shared__ float kt[DH][260];
    float* pbuf = &kt[0][0];            // reused: partials[4*576] + sim/attn[576]
    const int t    = threadIdx.x;
    const int widx = blockIdx.x;        // b*256 + wy*16 + wx
    const int h    = blockIdx.y;
    const int b  = widx >> 8;
    const int wy = (widx >> 4) & 15, wx = widx & 15;
    const int n  = t;
    const int gy = wy*WIN + (n >> 4), gx = wx*WIN + (n & 15);
    const size_t pbase = (size_t)h*PS + (size_t)((b*NHH + gy)*NWW + gx) * DH;

    // phase A: q,k transposed into LDS (fp32)
#pragma unroll
    for (int j8 = 0; j8 < 3; ++j8) {
        const u16x8 qv = *(const u16x8*)(q + pbase + j8*8);
        const u16x8 kv = *(const u16x8*)(k + pbase + j8*8);
#pragma unroll
        for (int j = 0; j < 8; ++j) { qt[j8*8+j][n] = b2f(qv[j]); kt[j8*8+j][n] = b2f(kv[j]); }
    }
    __syncthreads();

    // phase B: sim partials; wave covers 64 of n, thread = 3x3 (i,j) block
    const int wvi  = t >> 6;
    const int lane = t & 63;
    const int i0 = (lane >> 3) * 3, j0 = (lane & 7) * 3;
    float s[3][3];
#pragma unroll
    for (int a2 = 0; a2 < 3; ++a2)
#pragma unroll
        for (int c = 0; c < 3; ++c) s[a2][c] = 0.f;
    for (int nn = wvi*64; nn < wvi*64 + 64; nn += 4) {
        float4 qv[3], kv[3];
#pragma unroll
        for (int a2 = 0; a2 < 3; ++a2) {
            qv[a2] = *(const float4*)&qt[i0+a2][nn];
            kv[a2] = *(const float4*)&kt[j0+a2][nn];
        }
#pragma unroll
        for (int a2 = 0; a2 < 3; ++a2)
#pragma unroll
            for (int c = 0; c < 3; ++c)
                s[a2][c] += qv[a2].x*kv[c].x + qv[a2].y*kv[c].y + qv[a2].z*kv[c].z + qv[a2].w*kv[c].w;
    }
    __syncthreads();

    // phase C: partials -> kt-flat; v -> qt
#pragma unroll
    for (int a2 = 0; a2 < 3; ++a2)
#pragma unroll
        for (int c = 0; c < 3; ++c)
            pbuf[wvi*576 + (i0+a2)*24 + (j0+c)] = s[a2][c];
#pragma unroll
    for (int j8 = 0; j8 < 3; ++j8) {
        const u16x8 vv = *(const u16x8*)(v + pbase + j8*8);
#pragma unroll
        for (int j = 0; j < 8; ++j) qt[j8*8+j][n] = b2f(vv[j]);
    }
    __syncthreads();

    // phase D: reduce 4 wave-partials + rescale
    const float rsc = rescale[h];
    for (int e = t; e < 576; e += 256) {
        const float sum = pbuf[e] + pbuf[576+e] + pbuf[1152+e] + pbuf[1728+e];
        pbuf[2304 + e] = sum * rsc;
    }
    __syncthreads();

    // phase E: softmax over j per row i
    if (t < 24) {
        float* srow = pbuf + 2304 + t*24;
        float m = srow[0];
#pragma unroll
        for (int j = 1; j < 24; ++j) m = fmaxf(m, srow[j]);
        float ssum = 0.f;
#pragma unroll
        for (int j = 0; j < 24; ++j) { const float e_ = expf(srow[j] - m); srow[j] = e_; ssum += e_; }
        const float inv = 1.f / ssum;
#pragma unroll
        for (int j = 0; j < 24; ++j) srow[j] *= inv;
    }
    __syncthreads();

    // phase F: PV — thread (iw,nc): 6 i-rows x one 4-wide n-chunk
    const int nc = t & 63;
    const int ib = (t >> 6) * 6;
    float4 acc[6];
#pragma unroll
    for (int ii = 0; ii < 6; ++ii) acc[ii] = make_float4(0.f,0.f,0.f,0.f);
#pragma unroll
    for (int j = 0; j < 24; ++j) {
        const float4 vj = *(const float4*)&qt[j][nc*4];
        const float aw0 = pbuf[2304 + (ib+0)*24 + j];
        const float aw1 = pbuf[2304 + (ib+1)*24 + j];
        const float aw2 = pbuf[2304 + (ib+2)*24 + j];
        const float aw3 = pbuf[2304 + (ib+3)*24 + j];
        const float aw4 = pbuf[2304 + (ib+4)*24 + j];
        const float aw5 = pbuf[2304 + (ib+5)*24 + j];
        acc[0].x += aw0*vj.x; acc[0].y += aw0*vj.y; acc[0].z += aw0*vj.z; acc[0].w += aw0*vj.w;
        acc[1].x += aw1*vj.x; acc[1].y += aw1*vj.y; acc[1].z += aw1*vj.z; acc[1].w += aw1*vj.w;
        acc[2].x += aw2*vj.x; acc[2].y += aw2*vj.y; acc[2].z += aw2*vj.z; acc[2].w += aw2*vj.w;
        acc[3].x += aw3*vj.x; acc[3].y += aw3*vj.y; acc[3].z += aw3*vj.z; acc[3].w += aw3*vj.w;
        acc[4].x += aw4*vj.x; acc[4].y += aw4*vj.y; acc[4].z += aw4*vj.z; acc[4].w += aw4*vj.w;
        acc[5].x += aw5*vj.x; acc[5].y += aw5*vj.y; acc[5].z += aw5*vj.z; acc[5].w += aw5*vj.w;
    }
    __syncthreads();
    // phase G: stage output fp32 into qt
#pragma unroll
    for (int ii = 0; ii < 6; ++ii)
        *(float4*)&qt[ib+ii][nc*4] = acc[ii];
    __syncthreads();
    // phase H: coalesced bf16 store (3KB contiguous per wave)
#pragma unroll
    for (int j8 = 0; j8 < 3; ++j8) {
        u16x8 o;
#pragma unroll
        for (int j = 0; j < 8; ++j) o[j] = f2b(qt[j8*8+j][n]);
        *(u16x8*)(out + pbase + j8*8) = o;
    }
}

// ---------------------------------------------------------------------------
// K4: out-projection MFMA GEMM with LDS-staged A (coalesced) + staged fp32 out.
// ---------------------------------------------------------------------------
__global__ __launch_bounds__(256) void outproj_gemm(
    const u16* __restrict__ a, const u16* __restrict__ bpack, float* __restrict__ yf)
{
    __shared__ __align__(16) u16 At[64*192];    // 24,576 B (swizzled)
    __shared__ __align__(16) float Sf[32*196];  // 25,088 B
    const int t = threadIdx.x, l = t & 63, w = t >> 6;
    const int lr = l & 15, lg = l >> 4;
    const size_t p0 = (size_t)blockIdx.x * 64;

    // stage A-tile: coalesced within head planes (contiguous 4.6KB per plane)
#pragma unroll
    for (int i = 0; i < 6; ++i) {
        const int idx = t + i*256;          // 0..1535 = h*192 + r*3 + c8
        const int h = idx / 192;
        const int rem = idx - h*192;
        const int r = rem / 3, c8 = rem - r*3;
        const u16x8 vv = *(const u16x8*)(a + (size_t)h*PS + (p0 + r)*DH + c8*8);
        *(u16x8*)&At[r*192 + (((h*3 + c8) ^ (r & 7))*8)] = vv;
    }
    __syncthreads();

    f32x4 acc[4][3];
#pragma unroll
    for (int mt = 0; mt < 4; ++mt)
#pragma unroll
        for (int nt = 0; nt < 3; ++nt) acc[mt][nt] = (f32x4){0.f,0.f,0.f,0.f};
    const u16* bp = bpack + (size_t)3*36864 + (size_t)w*3*3072 + l*8;
#pragma unroll
    for (int ks = 0; ks < 6; ++ks) {
        bf16x8 af[4], bfr[3];
#pragma unroll
        for (int nt = 0; nt < 3; ++nt)
            bfr[nt] = *(const bf16x8*)(bp + (size_t)nt*3072 + ks*512);
#pragma unroll
        for (int mt = 0; mt < 4; ++mt)
            af[mt] = *(const bf16x8*)&At[(mt*16 + lr)*192 + ((ks*4 + lg) ^ (lr & 7))*8];
#pragma unroll
        for (int mt = 0; mt < 4; ++mt)
#pragma unroll
            for (int nt = 0; nt < 3; ++nt)
                acc[mt][nt] = __builtin_amdgcn_mfma_f32_16x16x32_bf16(
                    af[mt], bfr[nt], acc[mt][nt], 0, 0, 0);
    }
    // D layout: position = mt*16 + lg*4 + reg, channel = (w*3+nt)*16 + lr
#pragma unroll
    for (int h2 = 0; h2 < 2; ++h2) {
        if (h2) __syncthreads();            // prev drain readers done
#pragma unroll
        for (int mi = 0; mi < 2; ++mi) {
            const int mt = h2*2 + mi;
#pragma unroll
            for (int nt = 0; nt < 3; ++nt)
#pragma unroll
                for (int reg = 0; reg < 4; ++reg)
                    Sf[(mi*16 + lg*4 + reg)*196 + (w*3 + nt)*16 + lr] = acc[mt][nt][reg];
        }
        __syncthreads();
        // drain: 32 rows x 192 ch fp32, fully contiguous 4KB runs
#pragma unroll
        for (int i = 0; i < 6; ++i) {
            const int f = t + i*256;        // 32 rows x 48 float4
            const int row = f / 48, c4 = f - row*48;
            *(float4*)(yf + (p0 + h2*32 + row)*CH + c4*4) = *(const float4*)&Sf[row*196 + c4*4];
        }
    }
}

// ---------------------------------------------------------------------------
extern "C" void kernel_launch(void* const* d_in, const int* in_sizes, int n_in,
                              void* d_out, int out_size, void* d_ws, size_t ws_size,
                              hipStream_t stream)
{
    (void)in_sizes; (void)n_in; (void)out_size; (void)ws_size;
    const float* x     = (const float*)d_in[0];
    const float* ln_g  = (const float*)d_in[1];
    const float* ln_b  = (const float*)d_in[2];
    const float* wq1   = (const float*)d_in[3];
    const float* wq2   = (const float*)d_in[4];
    const float* wk1   = (const float*)d_in[5];
    const float* wk2   = (const float*)d_in[6];
    const float* wv1   = (const float*)d_in[7];
    const float* wv2   = (const float*)d_in[8];
    const float* rsc   = (const float*)d_in[9];
    const float* w_out = (const float*)d_in[10];
    float* out = (float*)d_out;

    const size_t NT = (size_t)NPOS * CH;    // 50,331,648 elems
    u16* u1 = (u16*)d_ws;                   // q,k,v pre-dwconv (head-sep)
    u16* u2 = u1 + NT;
    u16* u3 = u2 + NT;
    u16* u4 = u3 + NT;                      // q,k,v post-dwconv (disjoint)
    u16* u5 = u4 + NT;
    u16* u6 = u5 + NT;
    u16* pack = u6 + NT;                    // 147,456 u16
    u16* zpage = pack + 147456;             // 512 B zero page (16B-aligned)

    hipMemsetAsync(zpage, 0, 512, stream);
    prep_weights<<<72, 256, 0, stream>>>(wq1, wk1, wv1, w_out, pack);
    // fused LN + QKV GEMM -> head-separated q,k,v
    ln_qkv_gemm<<<NPOS/32, 256, 0, stream>>>(x, ln_g, ln_b, pack, u1, u2, u3);
    // depthwise 3x3: grid (1024 px-blocks x 9 subs, heads)
    dwconv_all<<<dim3(9216, HEADS), 256, 0, stream>>>(
        u1, u2, u3, wq2, wk2, wv2, u4, u5, u6, zpage);
    // windowed channel attention: q=u4, k=u5, v=u6 -> u1 (head-sep)
    attn_kernel<<<dim3(NB*256, HEADS), 256, 0, stream>>>(u4, u5, u6, rsc, u1);
    // output projection (A staged in LDS, fp32 NHWC out)
    outproj_gemm<<<NPOS/64, 256, 0, stream>>>(u1, pack, out);
}

// Round 12
// 564.500 us; speedup vs baseline: 1.1759x; 1.1759x over previous
//
#include <hip/hip_runtime.h>
#include <hip/hip_bf16.h>

#define CH    192
#define NB    4
#define NHH   256
#define NWW   256
#define NPOS  (NB*NHH*NWW)   // 262144
#define HEADS 8
#define DH    24
#define WIN   16
#define PS    ((size_t)NPOS*DH)   // head-plane stride (elems)

typedef unsigned short u16;
typedef __bf16 bf16x8 __attribute__((ext_vector_type(8)));
typedef float  f32x4  __attribute__((ext_vector_type(4)));
typedef u16    u16x8  __attribute__((ext_vector_type(8)));
typedef u16    u16x4  __attribute__((ext_vector_type(4)));

__device__ __forceinline__ float b2f(u16 h) {
    union { unsigned int u; float f; } x; x.u = ((unsigned int)h) << 16; return x.f;
}
__device__ __forceinline__ u16 f2b(float f) {   // RNE
    union { float f; unsigned int u; } x; x.f = f;
    return (u16)((x.u + 0x7fffu + ((x.u >> 16) & 1u)) >> 16);
}

// ---------------------------------------------------------------------------
// P0: pack 4 weight matrices (fp32 [o][i]) into MFMA fragment order, bf16.
// ---------------------------------------------------------------------------
__global__ __launch_bounds__(256) void prep_weights(
    const float* __restrict__ w0, const float* __restrict__ w1,
    const float* __restrict__ w2, const float* __restrict__ w3,
    u16* __restrict__ pack)
{
    const int t = blockIdx.x * 256 + threadIdx.x;   // 18432 total
    const int lane = t & 63, g = t >> 6;            // g: 0..287
    const int mat = g / 72;
    const float* w = (mat == 0) ? w0 : (mat == 1) ? w1 : (mat == 2) ? w2 : w3;
    const int nt = (g / 6) % 12, ks = g % 6;
    const float* src = w + (nt*16 + (lane & 15)) * CH + ks*32 + (lane >> 4) * 8;
    const float4 a = *(const float4*)(src);
    const float4 b = *(const float4*)(src + 4);
    u16x8 o;
    o[0]=f2b(a.x); o[1]=f2b(a.y); o[2]=f2b(a.z); o[3]=f2b(a.w);
    o[4]=f2b(b.x); o[5]=f2b(b.y); o[6]=f2b(b.z); o[7]=f2b(b.w);
    *(u16x8*)(pack + (size_t)g*512 + lane*8) = o;
}

// ---------------------------------------------------------------------------
// K1: fused LayerNorm + QKV MFMA GEMM (operand-swapped: D = W * X^T).
// M=32 tile, At swizzled, 25.1 KB LDS, 6 blk/CU. (unchanged)
// ---------------------------------------------------------------------------
__global__ __launch_bounds__(256, 6) void ln_qkv_gemm(
    const float* __restrict__ x, const float* __restrict__ lng, const float* __restrict__ lnb,
    const u16* __restrict__ bpack,
    u16* __restrict__ y0, u16* __restrict__ y1, u16* __restrict__ y2)
{
    __shared__ __align__(16) u16 At[32*192];    // 12,288 B (swizzled)
    __shared__ __align__(16) u16 St32[32*200];  // 12,800 B
    const int t = threadIdx.x, l = t & 63, w = t >> 6;
    const int lr = l & 15, lg = l >> 4;
    const size_t p0 = (size_t)blockIdx.x * 32;

    // ---- LN phase: 8 lanes per row (24 ch each), shfl-reduce, bf16 -> At ----
    {
        const int row = t >> 3, part = t & 7;
        const float* xp = x + (p0 + row) * CH + part * 24;
        float vals[24];
#pragma unroll
        for (int j = 0; j < 6; ++j) {
            float4 v4 = *(const float4*)(xp + j * 4);
            vals[j*4+0]=v4.x; vals[j*4+1]=v4.y; vals[j*4+2]=v4.z; vals[j*4+3]=v4.w;
        }
        float s = 0.f, s2 = 0.f;
#pragma unroll
        for (int j = 0; j < 24; ++j) { s += vals[j]; s2 += vals[j]*vals[j]; }
        s += __shfl_xor(s, 1);  s2 += __shfl_xor(s2, 1);
        s += __shfl_xor(s, 2);  s2 += __shfl_xor(s2, 2);
        s += __shfl_xor(s, 4);  s2 += __shfl_xor(s2, 4);
        const float mu = s * (1.f/192.f);
        const float rs = rsqrtf(s2 * (1.f/192.f) - mu*mu + 1e-5f);
#pragma unroll
        for (int jb = 0; jb < 3; ++jb) {
            u16x8 o;
#pragma unroll
            for (int j = 0; j < 8; ++j) {
                const int c = part*24 + jb*8 + j;
                o[j] = f2b((vals[jb*8+j] - mu) * rs * lng[c] + lnb[c]);
            }
            const int cb = part*3 + jb;               // 0..23
            *(u16x8*)&At[row*192 + (cb ^ (row & 7))*8] = o;
        }
    }
    __syncthreads();

    // ---- GEMM over 3 weight matrices (operand-swapped) ----
    for (int mat = 0; mat < 3; ++mat) {
        u16* yb = (mat == 0) ? y0 : (mat == 1) ? y1 : y2;
        f32x4 acc[2][3];
#pragma unroll
        for (int mt = 0; mt < 2; ++mt)
#pragma unroll
            for (int nt = 0; nt < 3; ++nt) acc[mt][nt] = (f32x4){0.f,0.f,0.f,0.f};
        const u16* bp = bpack + (size_t)mat*36864 + (size_t)w*3*3072 + l*8;
#pragma unroll
        for (int ks = 0; ks < 6; ++ks) {
            bf16x8 wf[3], xf[2];
#pragma unroll
            for (int nt = 0; nt < 3; ++nt)
                wf[nt] = *(const bf16x8*)(bp + (size_t)nt*3072 + ks*512);
#pragma unroll
            for (int mt = 0; mt < 2; ++mt)
                xf[mt] = *(const bf16x8*)&At[(mt*16 + lr)*192 + ((ks*4 + lg) ^ (lr & 7))*8];
#pragma unroll
            for (int mt = 0; mt < 2; ++mt)
#pragma unroll
                for (int nt = 0; nt < 3; ++nt)   // D = W-frag * X-frag
                    acc[mt][nt] = __builtin_amdgcn_mfma_f32_16x16x32_bf16(
                        wf[nt], xf[mt], acc[mt][nt], 0, 0, 0);
        }
        // D layout: position = mt*16 + lr, channel = (w*3+nt)*16 + lg*4 + reg
        __syncthreads();                 // St32 free (prev mat's drain done)
#pragma unroll
        for (int mt = 0; mt < 2; ++mt)
#pragma unroll
            for (int nt = 0; nt < 3; ++nt) {
                u16x4 pk;
                pk[0] = f2b(acc[mt][nt][0]); pk[1] = f2b(acc[mt][nt][1]);
                pk[2] = f2b(acc[mt][nt][2]); pk[3] = f2b(acc[mt][nt][3]);
                *(u16x4*)&St32[(mt*16 + lr)*200 + (w*3 + nt)*16 + lg*4] = pk;
            }
        __syncthreads();
        // drain: 256 threads = 8 heads x 32 rows, 48B contiguous each
        {
            const int hh = t >> 5, r = t & 31;
            u16* dst = yb + (size_t)hh*PS + (p0 + r)*DH;
#pragma unroll
            for (int j8 = 0; j8 < 3; ++j8)
                *(u16x8*)(dst + j8*8) = *(const u16x8*)&St32[r*200 + hh*24 + j8*8];
        }
    }
}

// ---------------------------------------------------------------------------
// K2: 3x3 depthwise conv per head-plane [h][b][y][x][24], bf16, fp32 accum.
// R10 structure (LDS weights [tap][c], batched iv[9], zpage borders, XCD
// band swizzle) + __launch_bounds__(256,4): R10/R11 showed the default
// occupancy heuristic caps VGPR at 32/20 and re-serializes the 9 tap loads;
// granting ~128 VGPR lets all 9 stay in flight (one vmcnt wait). 4 waves/
// SIMD with 2x MLP/wave beats 8 waves with serialized loads when
// latency-bound.
// ---------------------------------------------------------------------------
__global__ __launch_bounds__(256, 4) void dwconv_all(
    const u16* __restrict__ in0, const u16* __restrict__ in1, const u16* __restrict__ in2,
    const float* __restrict__ w0, const float* __restrict__ w1, const float* __restrict__ w2,
    u16* __restrict__ out0, u16* __restrict__ out1, u16* __restrict__ out2,
    const u16* __restrict__ zpage)
{
    __shared__ __align__(16) float wloc[9*DH];   // [tap][c], 864 B
    const int z = blockIdx.z;
    const u16* in  = (z == 0) ? in0  : (z == 1) ? in1  : in2;
    const float* wdw = (z == 0) ? w0 : (z == 1) ? w1 : w2;
    u16* out       = (z == 0) ? out0 : (z == 1) ? out1 : out2;
    const int t = threadIdx.x;
    const int h = blockIdx.y;
    if (t < 216) {                        // wdw layout [c][tap] -> wloc [tap][c]
        const int c = t / 9, tap = t - c*9;
        wloc[tap*DH + c] = wdw[h*216 + t];
    }
    __syncthreads();
    const int NSLICE = NPOS*3/256;           // 3072 blocks per (h,z) slice
    const int CPX = NSLICE/8;                // 384 contiguous blocks per XCD
    const int bx = blockIdx.x;
    const int swz = (bx & 7)*CPX + (bx >> 3);
    const int gid2 = swz * 256 + t;          // in [0, NPOS*3)
    const int p  = gid2 / 3, c8 = gid2 - p*3;
    const int x = p & 255, y = (p >> 8) & 255, b = p >> 16;
    const size_t plane = (size_t)h * PS;

    // issue all 9 tap loads (borders -> zero page), then one wait
    u16x8 iv[9];
#pragma unroll
    for (int ky = 0; ky < 3; ++ky) {
        const int yy = y + ky - 1;
        const bool oky = (yy >= 0) && (yy < NHH);
        const u16* rowp = in + plane + (size_t)((b*NHH + yy)*NWW + x)*DH + c8*8;
#pragma unroll
        for (int kx = 0; kx < 3; ++kx) {
            const int xx = x + kx - 1;
            const bool ok = oky && (xx >= 0) && (xx < NWW);
            const u16* src = ok ? (rowp + (kx - 1)*DH) : zpage;
            iv[ky*3 + kx] = *(const u16x8*)src;
        }
    }
    float acc[8] = {0,0,0,0,0,0,0,0};
#pragma unroll
    for (int tap = 0; tap < 9; ++tap) {
        float wr[8];
        *(float4*)&wr[0] = *(const float4*)&wloc[tap*DH + c8*8];
        *(float4*)&wr[4] = *(const float4*)&wloc[tap*DH + c8*8 + 4];
#pragma unroll
        for (int j = 0; j < 8; ++j)
            acc[j] += b2f(iv[tap][j]) * wr[j];
    }
    u16x8 ov;
#pragma unroll
    for (int j = 0; j < 8; ++j) ov[j] = f2b(acc[j]);
    *(u16x8*)(out + plane + (size_t)p*DH + c8*8) = ov;
}

// ---------------------------------------------------------------------------
// K3: per-(window, head) channel attention; head-separated I/O.
// ---------------------------------------------------------------------------
__global__ __launch_bounds__(256) void attn_kernel(
    const u16* __restrict__ q, const u16* __restrict__ k, const u16* __restrict__ v,
    const float* __restrict__ rescale, u16* __restrict__ out)
{
    __shared__ float qt[DH][260];
    __shared__ float kt[DH][260];
    float* pbuf = &kt[0][0];            // reused: partials[4*576] + sim/attn[576]
    const int t    = threadIdx.x;
    const int widx = blockIdx.x;        // b*256 + wy*16 + wx
    const int h    = blockIdx.y;
    const int b  = widx >> 8;
    const int wy = (widx >> 4) & 15, wx = widx & 15;
    const int n  = t;
    const int gy = wy*WIN + (n >> 4), gx = wx*WIN + (n & 15);
    const size_t pbase = (size_t)h*PS + (size_t)((b*NHH + gy)*NWW + gx) * DH;

    // phase A: q,k transposed into LDS (fp32)
#pragma unroll
    for (int j8 = 0; j8 < 3; ++j8) {
        const u16x8 qv = *(const u16x8*)(q + pbase + j8*8);
        const u16x8 kv = *(const u16x8*)(k + pbase + j8*8);
#pragma unroll
        for (int j = 0; j < 8; ++j) { qt[j8*8+j][n] = b2f(qv[j]); kt[j8*8+j][n] = b2f(kv[j]); }
    }
    __syncthreads();

    // phase B: sim partials; wave covers 64 of n, thread = 3x3 (i,j) block
    const int wvi  = t >> 6;
    const int lane = t & 63;
    const int i0 = (lane >> 3) * 3, j0 = (lane & 7) * 3;
    float s[3][3];
#pragma unroll
    for (int a2 = 0; a2 < 3; ++a2)
#pragma unroll
        for (int c = 0; c < 3; ++c) s[a2][c] = 0.f;
    for (int nn = wvi*64; nn < wvi*64 + 64; nn += 4) {
        float4 qv[3], kv[3];
#pragma unroll
        for (int a2 = 0; a2 < 3; ++a2) {
            qv[a2] = *(const float4*)&qt[i0+a2][nn];
            kv[a2] = *(const float4*)&kt[j0+a2][nn];
        }
#pragma unroll
        for (int a2 = 0; a2 < 3; ++a2)
#pragma unroll
            for (int c = 0; c < 3; ++c)
                s[a2][c] += qv[a2].x*kv[c].x + qv[a2].y*kv[c].y + qv[a2].z*kv[c].z + qv[a2].w*kv[c].w;
    }
    __syncthreads();

    // phase C: partials -> kt-flat; v -> qt
#pragma unroll
    for (int a2 = 0; a2 < 3; ++a2)
#pragma unroll
        for (int c = 0; c < 3; ++c)
            pbuf[wvi*576 + (i0+a2)*24 + (j0+c)] = s[a2][c];
#pragma unroll
    for (int j8 = 0; j8 < 3; ++j8) {
        const u16x8 vv = *(const u16x8*)(v + pbase + j8*8);
#pragma unroll
        for (int j = 0; j < 8; ++j) qt[j8*8+j][n] = b2f(vv[j]);
    }
    __syncthreads();

    // phase D: reduce 4 wave-partials + rescale
    const float rsc = rescale[h];
    for (int e = t; e < 576; e += 256) {
        const float sum = pbuf[e] + pbuf[576+e] + pbuf[1152+e] + pbuf[1728+e];
        pbuf[2304 + e] = sum * rsc;
    }
    __syncthreads();

    // phase E: softmax over j per row i
    if (t < 24) {
        float* srow = pbuf + 2304 + t*24;
        float m = srow[0];
#pragma unroll
        for (int j = 1; j < 24; ++j) m = fmaxf(m, srow[j]);
        float ssum = 0.f;
#pragma unroll
        for (int j = 0; j < 24; ++j) { const float e_ = expf(srow[j] - m); srow[j] = e_; ssum += e_; }
        const float inv = 1.f / ssum;
#pragma unroll
        for (int j = 0; j < 24; ++j) srow[j] *= inv;
    }
    __syncthreads();

    // phase F: PV — thread (iw,nc): 6 i-rows x one 4-wide n-chunk
    const int nc = t & 63;
    const int ib = (t >> 6) * 6;
    float4 acc[6];
#pragma unroll
    for (int ii = 0; ii < 6; ++ii) acc[ii] = make_float4(0.f,0.f,0.f,0.f);
#pragma unroll
    for (int j = 0; j < 24; ++j) {
        const float4 vj = *(const float4*)&qt[j][nc*4];
        const float aw0 = pbuf[2304 + (ib+0)*24 + j];
        const float aw1 = pbuf[2304 + (ib+1)*24 + j];
        const float aw2 = pbuf[2304 + (ib+2)*24 + j];
        const float aw3 = pbuf[2304 + (ib+3)*24 + j];
        const float aw4 = pbuf[2304 + (ib+4)*24 + j];
        const float aw5 = pbuf[2304 + (ib+5)*24 + j];
        acc[0].x += aw0*vj.x; acc[0].y += aw0*vj.y; acc[0].z += aw0*vj.z; acc[0].w += aw0*vj.w;
        acc[1].x += aw1*vj.x; acc[1].y += aw1*vj.y; acc[1].z += aw1*vj.z; acc[1].w += aw1*vj.w;
        acc[2].x += aw2*vj.x; acc[2].y += aw2*vj.y; acc[2].z += aw2*vj.z; acc[2].w += aw2*vj.w;
        acc[3].x += aw3*vj.x; acc[3].y += aw3*vj.y; acc[3].z += aw3*vj.z; acc[3].w += aw3*vj.w;
        acc[4].x += aw4*vj.x; acc[4].y += aw4*vj.y; acc[4].z += aw4*vj.z; acc[4].w += aw4*vj.w;
        acc[5].x += aw5*vj.x; acc[5].y += aw5*vj.y; acc[5].z += aw5*vj.z; acc[5].w += aw5*vj.w;
    }
    __syncthreads();
    // phase G: stage output fp32 into qt
#pragma unroll
    for (int ii = 0; ii < 6; ++ii)
        *(float4*)&qt[ib+ii][nc*4] = acc[ii];
    __syncthreads();
    // phase H: coalesced bf16 store (3KB contiguous per wave)
#pragma unroll
    for (int j8 = 0; j8 < 3; ++j8) {
        u16x8 o;
#pragma unroll
        for (int j = 0; j < 8; ++j) o[j] = f2b(qt[j8*8+j][n]);
        *(u16x8*)(out + pbase + j8*8) = o;
    }
}

// ---------------------------------------------------------------------------
// K4: out-projection MFMA GEMM with LDS-staged A (coalesced) + staged fp32 out.
// ---------------------------------------------------------------------------
__global__ __launch_bounds__(256) void outproj_gemm(
    const u16* __restrict__ a, const u16* __restrict__ bpack, float* __restrict__ yf)
{
    __shared__ __align__(16) u16 At[64*192];    // 24,576 B (swizzled)
    __shared__ __align__(16) float Sf[32*196];  // 25,088 B
    const int t = threadIdx.x, l = t & 63, w = t >> 6;
    const int lr = l & 15, lg = l >> 4;
    const size_t p0 = (size_t)blockIdx.x * 64;

    // stage A-tile: coalesced within head planes (contiguous 4.6KB per plane)
#pragma unroll
    for (int i = 0; i < 6; ++i) {
        const int idx = t + i*256;          // 0..1535 = h*192 + r*3 + c8
        const int h = idx / 192;
        const int rem = idx - h*192;
        const int r = rem / 3, c8 = rem - r*3;
        const u16x8 vv = *(const u16x8*)(a + (size_t)h*PS + (p0 + r)*DH + c8*8);
        *(u16x8*)&At[r*192 + (((h*3 + c8) ^ (r & 7))*8)] = vv;
    }
    __syncthreads();

    f32x4 acc[4][3];
#pragma unroll
    for (int mt = 0; mt < 4; ++mt)
#pragma unroll
        for (int nt = 0; nt < 3; ++nt) acc[mt][nt] = (f32x4){0.f,0.f,0.f,0.f};
    const u16* bp = bpack + (size_t)3*36864 + (size_t)w*3*3072 + l*8;
#pragma unroll
    for (int ks = 0; ks < 6; ++ks) {
        bf16x8 af[4], bfr[3];
#pragma unroll
        for (int nt = 0; nt < 3; ++nt)
            bfr[nt] = *(const bf16x8*)(bp + (size_t)nt*3072 + ks*512);
#pragma unroll
        for (int mt = 0; mt < 4; ++mt)
            af[mt] = *(const bf16x8*)&At[(mt*16 + lr)*192 + ((ks*4 + lg) ^ (lr & 7))*8];
#pragma unroll
        for (int mt = 0; mt < 4; ++mt)
#pragma unroll
            for (int nt = 0; nt < 3; ++nt)
                acc[mt][nt] = __builtin_amdgcn_mfma_f32_16x16x32_bf16(
                    af[mt], bfr[nt], acc[mt][nt], 0, 0, 0);
    }
    // D layout: position = mt*16 + lg*4 + reg, channel = (w*3+nt)*16 + lr
#pragma unroll
    for (int h2 = 0; h2 < 2; ++h2) {
        if (h2) __syncthreads();            // prev drain readers done
#pragma unroll
        for (int mi = 0; mi < 2; ++mi) {
            const int mt = h2*2 + mi;
#pragma unroll
            for (int nt = 0; nt < 3; ++nt)
#pragma unroll
                for (int reg = 0; reg < 4; ++reg)
                    Sf[(mi*16 + lg*4 + reg)*196 + (w*3 + nt)*16 + lr] = acc[mt][nt][reg];
        }
        __syncthreads();
        // drain: 32 rows x 192 ch fp32, fully contiguous 4KB runs
#pragma unroll
        for (int i = 0; i < 6; ++i) {
            const int f = t + i*256;        // 32 rows x 48 float4
            const int row = f / 48, c4 = f - row*48;
            *(float4*)(yf + (p0 + h2*32 + row)*CH + c4*4) = *(const float4*)&Sf[row*196 + c4*4];
        }
    }
}

// ---------------------------------------------------------------------------
extern "C" void kernel_launch(void* const* d_in, const int* in_sizes, int n_in,
                              void* d_out, int out_size, void* d_ws, size_t ws_size,
                              hipStream_t stream)
{
    (void)in_sizes; (void)n_in; (void)out_size; (void)ws_size;
    const float* x     = (const float*)d_in[0];
    const float* ln_g  = (const float*)d_in[1];
    const float* ln_b  = (const float*)d_in[2];
    const float* wq1   = (const float*)d_in[3];
    const float* wq2   = (const float*)d_in[4];
    const float* wk1   = (const float*)d_in[5];
    const float* wk2   = (const float*)d_in[6];
    const float* wv1   = (const float*)d_in[7];
    const float* wv2   = (const float*)d_in[8];
    const float* rsc   = (const float*)d_in[9];
    const float* w_out = (const float*)d_in[10];
    float* out = (float*)d_out;

    const size_t NT = (size_t)NPOS * CH;    // 50,331,648 elems
    u16* u1 = (u16*)d_ws;                   // q,k,v pre-dwconv (head-sep)
    u16* u2 = u1 + NT;
    u16* u3 = u2 + NT;
    u16* u4 = u3 + NT;                      // q,k,v post-dwconv (disjoint)
    u16* u5 = u4 + NT;
    u16* u6 = u5 + NT;
    u16* pack = u6 + NT;                    // 147,456 u16
    u16* zpage = pack + 147456;             // 512 B zero page (16B-aligned)

    hipMemsetAsync(zpage, 0, 512, stream);
    prep_weights<<<72, 256, 0, stream>>>(wq1, wk1, wv1, w_out, pack);
    // fused LN + QKV GEMM -> head-separated q,k,v
    ln_qkv_gemm<<<NPOS/32, 256, 0, stream>>>(x, ln_g, ln_b, pack, u1, u2, u3);
    // depthwise 3x3, one dispatch (z = tensor): u1->u4, u2->u5, u3->u6
    dwconv_all<<<dim3(NPOS*3/256, HEADS, 3), 256, 0, stream>>>(
        u1, u2, u3, wq2, wk2, wv2, u4, u5, u6, zpage);
    // windowed channel attention: q=u4, k=u5, v=u6 -> u1 (head-sep)
    attn_kernel<<<dim3(NB*256, HEADS), 256, 0, stream>>>(u4, u5, u6, rsc, u1);
    // output projection (A staged in LDS, fp32 NHWC out)
    outproj_gemm<<<NPOS/64, 256, 0, stream>>>(u1, pack, out);
}